// Round 2
// baseline (615.388 us; speedup 1.0000x reference)
//
#include <hip/hip_runtime.h>
#include <math.h>

#define NN 50000
#define NE 800000
#define FF 128
#define NH 8

using short8 = __attribute__((ext_vector_type(8))) short;
using f32x4  = __attribute__((ext_vector_type(4))) float;

__device__ __forceinline__ short f2bf(float x){
  union { float f; unsigned u; } c; c.f = x;
  unsigned r = c.u + 0x7FFFu + ((c.u >> 16) & 1u);
  return (short)(r >> 16);
}
__device__ __forceinline__ float bf2f(short h){
  union { unsigned u; float f; } c; c.u = ((unsigned)(unsigned short)h) << 16;
  return c.f;
}

// ---- weight conversion: f32 -> split bf16 (hi, lo); layout: [hi array | lo array]
// bc = [Wedge ; Wgate] stacked [16,128]
__global__ void k_cvt_w(const float* __restrict__ Wq, const float* __restrict__ Wk,
                        const float* __restrict__ Wv, const float* __restrict__ Wn,
                        const float* __restrict__ We, const float* __restrict__ Wg,
                        short* bq, short* bk, short* bv, short* bn, short* bc){
  int i = blockIdx.x*256 + threadIdx.x;
  if (i < 16384){
    const float* W[4] = {Wq, Wk, Wv, Wn};
    short* B[4] = {bq, bk, bv, bn};
    #pragma unroll
    for (int j = 0; j < 4; j++){
      float x = W[j][i];
      short hi = f2bf(x);
      short lo = f2bf(x - bf2f(hi));
      B[j][i] = hi; B[j][i + 16384] = lo;
    }
  }
  if (i < 2048){
    float x = (i < 1024) ? We[i] : Wg[i-1024];
    short hi = f2bf(x);
    short lo = f2bf(x - bf2f(hi));
    bc[i] = hi; bc[i + 2048] = lo;
  }
}

// ---- C[M,NC] = A[M,128] (f32, split->bf16 hi/lo) @ B[NC,128]^T (split bf16)
// B layout: [NC*128 hi | NC*128 lo]. 3 MFMAs per k-chunk: hi*hi + hi*lo + lo*hi
__global__ void k_gemm_bt(const float* __restrict__ A, const short* __restrict__ B,
                          float* __restrict__ C, int M, int NC){
  int w = threadIdx.x >> 6, lane = threadIdx.x & 63;
  int row0 = (blockIdx.x*4 + w)*16;
  if (row0 >= M) return;
  int r  = lane & 15;       // A row within tile / B col / C col
  int kq = lane >> 4;       // k-chunk group

  const short* Bhi = B;
  const short* Blo = B + (size_t)NC*FF;

  short8 ahi[4], alo[4];
  const float* arow = A + (size_t)(row0 + r)*FF + kq*8;
  #pragma unroll
  for (int kk = 0; kk < 4; kk++){
    float4 lo4 = *(const float4*)(arow + kk*32);
    float4 hi4 = *(const float4*)(arow + kk*32 + 4);
    float xs[8] = {lo4.x, lo4.y, lo4.z, lo4.w, hi4.x, hi4.y, hi4.z, hi4.w};
    short8 th, tl;
    #pragma unroll
    for (int j = 0; j < 8; j++){
      short h = f2bf(xs[j]);
      th[j] = h;
      tl[j] = f2bf(xs[j] - bf2f(h));
    }
    ahi[kk] = th; alo[kk] = tl;
  }

  for (int ct = 0; ct < (NC >> 4); ct++){
    f32x4 acc = {0.f,0.f,0.f,0.f};
    const short* bh = Bhi + (size_t)(ct*16 + r)*FF + kq*8;
    const short* bl = Blo + (size_t)(ct*16 + r)*FF + kq*8;
    #pragma unroll
    for (int kk = 0; kk < 4; kk++){
      short8 bfh = *(const short8*)(bh + kk*32);
      short8 bfl = *(const short8*)(bl + kk*32);
      acc = __builtin_amdgcn_mfma_f32_16x16x32_bf16(ahi[kk], bfh, acc, 0, 0, 0);
      acc = __builtin_amdgcn_mfma_f32_16x16x32_bf16(ahi[kk], bfl, acc, 0, 0, 0);
      acc = __builtin_amdgcn_mfma_f32_16x16x32_bf16(alo[kk], bfh, acc, 0, 0, 0);
    }
    // D layout: col = lane&15, row = (lane>>4)*4 + reg   [measured m89/m91]
    float* crow = C + (size_t)(row0 + kq*4)*NC + ct*16 + r;
    #pragma unroll
    for (int i = 0; i < 4; i++) crow[(size_t)i*NC] = acc[i];
  }
}

// ---- CSR build: histogram, 1-block scan, scatter
__global__ void k_hist(const int* __restrict__ dst, int* __restrict__ deg){
  int e = blockIdx.x*256 + threadIdx.x;
  if (e < NE) atomicAdd(&deg[dst[e]], 1);
}

__global__ void k_scan(const int* __restrict__ deg, int* __restrict__ rowptr,
                       int* __restrict__ cursor){
  __shared__ int sums[1024];
  const int CH = 49;                      // 1024*49 = 50176 >= 50000
  int t = threadIdx.x;
  int base = t*CH;
  int s = 0;
  for (int i = 0; i < CH; i++){ int idx = base+i; if (idx < NN) s += deg[idx]; }
  sums[t] = s; __syncthreads();
  for (int off = 1; off < 1024; off <<= 1){
    int val = (t >= off) ? sums[t-off] : 0;
    __syncthreads();
    sums[t] += val;
    __syncthreads();
  }
  int run = sums[t] - s;                  // exclusive prefix for this chunk
  for (int i = 0; i < CH; i++){
    int idx = base+i;
    if (idx < NN){ rowptr[idx] = run; cursor[idx] = run; run += deg[idx]; }
  }
}

__global__ void k_scatter(const int* __restrict__ src, const int* __restrict__ dst,
                          int* __restrict__ cursor, int2* __restrict__ list){
  int e = blockIdx.x*256 + threadIdx.x;
  if (e < NE){
    int d = dst[e];
    int pos = atomicAdd(&cursor[d], 1);
    list[pos] = make_int2(src[e], e);
  }
}

// ---- fused per-dst: QK dot + bias + clamp + scale + online softmax + gated PV agg
// one wave per node; lane owns features f = 2*lane, 2*lane+1; head h = lane>>3
__global__ void k_aggregate(const float* __restrict__ q, const float* __restrict__ k,
                            const float* __restrict__ v, const float* __restrict__ ebg,
                            const int* __restrict__ rowptr, const int* __restrict__ cursor,
                            const int2* __restrict__ list, float* __restrict__ agg){
  int w = threadIdx.x >> 6, lane = threadIdx.x & 63;
  int node = blockIdx.x*4 + w;
  if (node >= NN) return;
  int beg = rowptr[node], end = cursor[node];
  float2 kk = *(const float2*)&k[(size_t)node*FF + lane*2];
  int h = lane >> 3;
  float m = -INFINITY, ssum = 0.f, acc0 = 0.f, acc1 = 0.f;
  for (int i = beg; i < end; i++){
    int2 es = list[i];
    int s = es.x, e = es.y;
    float2 qq = *(const float2*)&q[(size_t)s*FF + lane*2];
    float p = qq.x*kk.x + qq.y*kk.y;
    p += __shfl_xor(p, 1); p += __shfl_xor(p, 2); p += __shfl_xor(p, 4);
    float bg   = ebg[(size_t)e*16 + (lane & 15)];
    float bias = __shfl(bg, h);
    float gpre = __shfl(bg, 8 + h);
    float a = fminf(fmaxf(p, -5.f), 5.f);
    float logit = (a + bias)*4.0f;            // /SCALING, SCALING = 1/sqrt(16)
    float mnew = fmaxf(m, logit);
    float corr = __expf(m - mnew);
    float t    = __expf(logit - mnew);
    float g    = 1.f/(1.f + __expf(-gpre));   // sigmoid
    float wgt  = t*g;
    float2 vv = *(const float2*)&v[(size_t)s*FF + lane*2];
    acc0 = acc0*corr + wgt*vv.x;
    acc1 = acc1*corr + wgt*vv.y;
    ssum = ssum*corr + t;
    m = mnew;
  }
  float inv = (end > beg) ? 1.f/ssum : 0.f;
  *(float2*)&agg[(size_t)node*FF + lane*2] = make_float2(acc0*inv, acc1*inv);
}

extern "C" void kernel_launch(void* const* d_in, const int* in_sizes, int n_in,
                              void* d_out, int out_size, void* d_ws, size_t ws_size,
                              hipStream_t stream) {
  const float* feat      = (const float*)d_in[0];
  const float* edge_feat = (const float*)d_in[1];
  const float* Wq        = (const float*)d_in[2];
  const float* Wk        = (const float*)d_in[3];
  const float* Wv        = (const float*)d_in[4];
  const float* Wnode     = (const float*)d_in[5];
  const float* Wedge     = (const float*)d_in[6];
  const float* Wgate     = (const float*)d_in[7];
  const int*   src       = (const int*)d_in[8];
  const int*   dst       = (const int*)d_in[9];
  float* out = (float*)d_out;

  char* p = (char*)d_ws;
  auto alloc = [&](size_t bytes)->char*{
    char* r = p; p += (bytes + 255) & ~(size_t)255; return r;
  };
  float* q      = (float*)alloc((size_t)NN*FF*4);
  float* kbuf   = (float*)alloc((size_t)NN*FF*4);
  float* v      = (float*)alloc((size_t)NN*FF*4);
  float* ebg    = (float*)alloc((size_t)NE*16*4);
  float* agg    = (float*)alloc((size_t)NN*FF*4);
  int*   deg    = (int*)  alloc((size_t)NN*4);
  int*   rowptr = (int*)  alloc((size_t)NN*4);
  int*   cursor = (int*)  alloc((size_t)NN*4);
  int2*  list   = (int2*) alloc((size_t)NE*8);
  short* bq     = (short*)alloc(2*16384*2);
  short* bk     = (short*)alloc(2*16384*2);
  short* bv     = (short*)alloc(2*16384*2);
  short* bn     = (short*)alloc(2*16384*2);
  short* bc     = (short*)alloc(2*2048*2);

  hipMemsetAsync(deg, 0, (size_t)NN*4, stream);

  k_cvt_w<<<64, 256, 0, stream>>>(Wq, Wk, Wv, Wnode, Wedge, Wgate, bq, bk, bv, bn, bc);

  int gemm_grid_n = (NN/16 + 3)/4;   // 782
  k_gemm_bt<<<gemm_grid_n, 256, 0, stream>>>(feat, bq, q,    NN, FF);
  k_gemm_bt<<<gemm_grid_n, 256, 0, stream>>>(feat, bk, kbuf, NN, FF);
  k_gemm_bt<<<gemm_grid_n, 256, 0, stream>>>(feat, bv, v,    NN, FF);

  k_gemm_bt<<<NE/64, 256, 0, stream>>>(edge_feat, bc, ebg, NE, 16);

  k_hist<<<(NE+255)/256, 256, 0, stream>>>(dst, deg);
  k_scan<<<1, 1024, 0, stream>>>(deg, rowptr, cursor);
  k_scatter<<<(NE+255)/256, 256, 0, stream>>>(src, dst, cursor, list);

  k_aggregate<<<(NN+3)/4, 256, 0, stream>>>(q, kbuf, v, ebg, rowptr, cursor, list, agg);

  k_gemm_bt<<<gemm_grid_n, 256, 0, stream>>>(agg, bn, out, NN, FF);
}

// Round 3
// 592.174 us; speedup vs baseline: 1.0392x; 1.0392x over previous
//
#include <hip/hip_runtime.h>
#include <math.h>

#define NN 50000
#define NE 800000
#define FF 128
#define NH 8

using short8 = __attribute__((ext_vector_type(8))) short;
using f32x4  = __attribute__((ext_vector_type(4))) float;

__device__ __forceinline__ short f2bf(float x){
  union { float f; unsigned u; } c; c.f = x;
  unsigned r = c.u + 0x7FFFu + ((c.u >> 16) & 1u);
  return (short)(r >> 16);
}
__device__ __forceinline__ float bf2f(short h){
  union { unsigned u; float f; } c; c.u = ((unsigned)(unsigned short)h) << 16;
  return c.f;
}

// ---- weight conversion f32 -> split bf16 (hi|lo), plus deg zero-init.
// bqkv = [Wq;Wk;Wv] stacked [384,128]: hi at [0,49152), lo at [49152, 98304)
// bn   = Wnode [128,128]: hi | lo
// bc   = [Wedge;Wgate] [16,128]: hi | lo
__global__ void k_cvt_w(const float* __restrict__ Wq, const float* __restrict__ Wk,
                        const float* __restrict__ Wv, const float* __restrict__ Wn,
                        const float* __restrict__ We, const float* __restrict__ Wg,
                        short* bqkv, short* bn, short* bc, int* __restrict__ deg){
  int i = blockIdx.x*256 + threadIdx.x;
  if (i < NN) deg[i] = 0;
  if (i < 16384){
    const float* W[3] = {Wq, Wk, Wv};
    #pragma unroll
    for (int j = 0; j < 3; j++){
      float x = W[j][i];
      short hi = f2bf(x);
      bqkv[j*16384 + i] = hi;
      bqkv[49152 + j*16384 + i] = f2bf(x - bf2f(hi));
    }
    float xn = Wn[i];
    short hn = f2bf(xn);
    bn[i] = hn; bn[i + 16384] = f2bf(xn - bf2f(hn));
  }
  if (i < 2048){
    float x = (i < 1024) ? We[i] : Wg[i-1024];
    short hi = f2bf(x);
    bc[i] = hi; bc[i + 2048] = f2bf(x - bf2f(hi));
  }
}

// ---- C[M,NC] = A[M,128] (f32, split->bf16 hi/lo) @ B[NC,128]^T (split bf16)
// B layout: [NC*128 hi | NC*128 lo]. 3 MFMAs per k-chunk: hi*hi + hi*lo + lo*hi
__global__ void k_gemm_bt(const float* __restrict__ A, const short* __restrict__ B,
                          float* __restrict__ C, int M, int NC){
  int w = threadIdx.x >> 6, lane = threadIdx.x & 63;
  int row0 = (blockIdx.x*4 + w)*16;
  if (row0 >= M) return;
  int r  = lane & 15;       // A row within tile / B col / C col
  int kq = lane >> 4;       // k-chunk group

  const short* Bhi = B;
  const short* Blo = B + (size_t)NC*FF;

  short8 ahi[4], alo[4];
  const float* arow = A + (size_t)(row0 + r)*FF + kq*8;
  #pragma unroll
  for (int kk = 0; kk < 4; kk++){
    float4 lo4 = *(const float4*)(arow + kk*32);
    float4 hi4 = *(const float4*)(arow + kk*32 + 4);
    float xs[8] = {lo4.x, lo4.y, lo4.z, lo4.w, hi4.x, hi4.y, hi4.z, hi4.w};
    short8 th, tl;
    #pragma unroll
    for (int j = 0; j < 8; j++){
      short h = f2bf(xs[j]);
      th[j] = h;
      tl[j] = f2bf(xs[j] - bf2f(h));
    }
    ahi[kk] = th; alo[kk] = tl;
  }

  for (int ct = 0; ct < (NC >> 4); ct++){
    f32x4 acc = {0.f,0.f,0.f,0.f};
    const short* bh = Bhi + (size_t)(ct*16 + r)*FF + kq*8;
    const short* bl = Blo + (size_t)(ct*16 + r)*FF + kq*8;
    #pragma unroll
    for (int kk = 0; kk < 4; kk++){
      short8 bfh = *(const short8*)(bh + kk*32);
      short8 bfl = *(const short8*)(bl + kk*32);
      acc = __builtin_amdgcn_mfma_f32_16x16x32_bf16(ahi[kk], bfh, acc, 0, 0, 0);
      acc = __builtin_amdgcn_mfma_f32_16x16x32_bf16(ahi[kk], bfl, acc, 0, 0, 0);
      acc = __builtin_amdgcn_mfma_f32_16x16x32_bf16(alo[kk], bfh, acc, 0, 0, 0);
    }
    // D layout: col = lane&15, row = (lane>>4)*4 + reg   [measured m89/m91]
    float* crow = C + (size_t)(row0 + kq*4)*NC + ct*16 + r;
    #pragma unroll
    for (int i = 0; i < 4; i++) crow[(size_t)i*NC] = acc[i];
  }
}

// ---- CSR build: histogram, 1-block scan, scatter
__global__ void k_hist(const int* __restrict__ dst, int* __restrict__ deg){
  int e = blockIdx.x*256 + threadIdx.x;
  if (e < NE) atomicAdd(&deg[dst[e]], 1);
}

__global__ void k_scan(const int* __restrict__ deg, int* __restrict__ rowptr,
                       int* __restrict__ cursor){
  __shared__ int sums[1024];
  const int CH = 49;                      // 1024*49 = 50176 >= 50000
  int t = threadIdx.x;
  int base = t*CH;
  int s = 0;
  for (int i = 0; i < CH; i++){ int idx = base+i; if (idx < NN) s += deg[idx]; }
  sums[t] = s; __syncthreads();
  for (int off = 1; off < 1024; off <<= 1){
    int val = (t >= off) ? sums[t-off] : 0;
    __syncthreads();
    sums[t] += val;
    __syncthreads();
  }
  int run = sums[t] - s;                  // exclusive prefix for this chunk
  for (int i = 0; i < CH; i++){
    int idx = base+i;
    if (idx < NN){ rowptr[idx] = run; cursor[idx] = run; run += deg[idx]; }
  }
}

__global__ void k_scatter(const int* __restrict__ src, const int* __restrict__ dst,
                          int* __restrict__ cursor, int2* __restrict__ list){
  int e = blockIdx.x*256 + threadIdx.x;
  if (e < NE){
    int d = dst[e];
    int pos = atomicAdd(&cursor[d], 1);
    list[pos] = make_int2(src[e], e);
  }
}

// ---- fused per-dst: QK dot + bias + clamp + scale + online softmax + gated PV agg
// one wave per node; lane owns features f = 2*lane, 2*lane+1; head h = lane>>3
// qkv is [N, 384]: q cols 0-127, k cols 128-255, v cols 256-383
__global__ void k_aggregate(const float* __restrict__ qkv, const float* __restrict__ ebg,
                            const int* __restrict__ rowptr, const int* __restrict__ cursor,
                            const int2* __restrict__ list, float* __restrict__ agg){
  int w = threadIdx.x >> 6, lane = threadIdx.x & 63;
  int node = blockIdx.x*4 + w;
  if (node >= NN) return;
  int beg = rowptr[node], end = cursor[node];
  float2 kk = *(const float2*)&qkv[(size_t)node*384 + 128 + lane*2];
  int h = lane >> 3;
  float m = -INFINITY, ssum = 0.f, acc0 = 0.f, acc1 = 0.f;
  for (int i = beg; i < end; i++){
    int2 es = list[i];
    int s = es.x, e = es.y;
    const float* srow = &qkv[(size_t)s*384 + lane*2];
    float2 qq = *(const float2*)srow;
    float p = qq.x*kk.x + qq.y*kk.y;
    p += __shfl_xor(p, 1); p += __shfl_xor(p, 2); p += __shfl_xor(p, 4);
    float bg   = ebg[(size_t)e*16 + (lane & 15)];
    float bias = __shfl(bg, h);
    float gpre = __shfl(bg, 8 + h);
    float a = fminf(fmaxf(p, -5.f), 5.f);
    float logit = (a + bias)*4.0f;            // /SCALING, SCALING = 1/sqrt(16)
    float mnew = fmaxf(m, logit);
    float corr = __expf(m - mnew);
    float t    = __expf(logit - mnew);
    float g    = 1.f/(1.f + __expf(-gpre));   // sigmoid
    float wgt  = t*g;
    float2 vv = *(const float2*)(srow + 256);
    acc0 = acc0*corr + wgt*vv.x;
    acc1 = acc1*corr + wgt*vv.y;
    ssum = ssum*corr + t;
    m = mnew;
  }
  float inv = (end > beg) ? 1.f/ssum : 0.f;
  *(float2*)&agg[(size_t)node*FF + lane*2] = make_float2(acc0*inv, acc1*inv);
}

extern "C" void kernel_launch(void* const* d_in, const int* in_sizes, int n_in,
                              void* d_out, int out_size, void* d_ws, size_t ws_size,
                              hipStream_t stream) {
  const float* feat      = (const float*)d_in[0];
  const float* edge_feat = (const float*)d_in[1];
  const float* Wq        = (const float*)d_in[2];
  const float* Wk        = (const float*)d_in[3];
  const float* Wv        = (const float*)d_in[4];
  const float* Wnode     = (const float*)d_in[5];
  const float* Wedge     = (const float*)d_in[6];
  const float* Wgate     = (const float*)d_in[7];
  const int*   src       = (const int*)d_in[8];
  const int*   dst       = (const int*)d_in[9];
  float* out = (float*)d_out;

  char* p = (char*)d_ws;
  auto alloc = [&](size_t bytes)->char*{
    char* r = p; p += (bytes + 255) & ~(size_t)255; return r;
  };
  float* qkv    = (float*)alloc((size_t)NN*384*4);
  float* ebg    = (float*)alloc((size_t)NE*16*4);
  float* agg    = (float*)alloc((size_t)NN*FF*4);
  int*   deg    = (int*)  alloc((size_t)NN*4);
  int*   rowptr = (int*)  alloc((size_t)NN*4);
  int*   cursor = (int*)  alloc((size_t)NN*4);
  int2*  list   = (int2*) alloc((size_t)NE*8);
  short* bqkv   = (short*)alloc(2*49152*2);
  short* bn     = (short*)alloc(2*16384*2);
  short* bc     = (short*)alloc(2*2048*2);

  k_cvt_w<<<196, 256, 0, stream>>>(Wq, Wk, Wv, Wnode, Wedge, Wgate, bqkv, bn, bc, deg);

  int gemm_grid_n = (NN/16 + 3)/4;   // 782
  k_gemm_bt<<<gemm_grid_n, 256, 0, stream>>>(feat, bqkv, qkv, NN, 384);
  k_gemm_bt<<<NE/64, 256, 0, stream>>>(edge_feat, bc, ebg, NE, 16);

  k_hist<<<(NE+255)/256, 256, 0, stream>>>(dst, deg);
  k_scan<<<1, 1024, 0, stream>>>(deg, rowptr, cursor);
  k_scatter<<<(NE+255)/256, 256, 0, stream>>>(src, dst, cursor, list);

  k_aggregate<<<(NN+3)/4, 256, 0, stream>>>(qkv, ebg, rowptr, cursor, list, agg);

  k_gemm_bt<<<gemm_grid_n, 256, 0, stream>>>(agg, bn, out, NN, FF);
}

// Round 4
// 537.611 us; speedup vs baseline: 1.1447x; 1.1015x over previous
//
#include <hip/hip_runtime.h>
#include <hip/hip_fp16.h>
#include <math.h>

#define NN 50000
#define NE 800000
#define FF 128

using short8 = __attribute__((ext_vector_type(8))) short;
using f32x4  = __attribute__((ext_vector_type(4))) float;

__device__ __forceinline__ short f2bf(float x){
  union { float f; unsigned u; } c; c.f = x;
  unsigned r = c.u + 0x7FFFu + ((c.u >> 16) & 1u);
  return (short)(r >> 16);
}
__device__ __forceinline__ float bf2f(short h){
  union { unsigned u; float f; } c; c.u = ((unsigned)(unsigned short)h) << 16;
  return c.f;
}

// ---- weight conversion f32 -> split bf16 (hi|lo), plus deg zero-init.
// bqkv = [Wq;Wk;Wv] stacked [384,128]: hi | lo;  bn = Wnode hi | lo;  bc = [Wedge;Wgate] hi | lo
__global__ void k_cvt_w(const float* __restrict__ Wq, const float* __restrict__ Wk,
                        const float* __restrict__ Wv, const float* __restrict__ Wn,
                        const float* __restrict__ We, const float* __restrict__ Wg,
                        short* bqkv, short* bn, short* bc, int* __restrict__ deg){
  int i = blockIdx.x*256 + threadIdx.x;
  if (i < NN) deg[i] = 0;
  if (i < 16384){
    const float* W[3] = {Wq, Wk, Wv};
    #pragma unroll
    for (int j = 0; j < 3; j++){
      float x = W[j][i];
      short hi = f2bf(x);
      bqkv[j*16384 + i] = hi;
      bqkv[49152 + j*16384 + i] = f2bf(x - bf2f(hi));
    }
    float xn = Wn[i];
    short hn = f2bf(xn);
    bn[i] = hn; bn[i + 16384] = f2bf(xn - bf2f(hn));
  }
  if (i < 2048){
    float x = (i < 1024) ? We[i] : Wg[i-1024];
    short hi = f2bf(x);
    bc[i] = hi; bc[i + 2048] = f2bf(x - bf2f(hi));
  }
}

// ---- C[M,NC] = A[M,128] (f32, split->bf16 hi/lo) @ B[NC,128]^T (split bf16)
// B layout: [NC*128 hi | NC*128 lo]. 3 MFMAs per k-chunk: hi*hi + hi*lo + lo*hi
// HALF_OUT: store fp16 (for gather buffers), else f32.
template<bool HALF_OUT>
__global__ void k_gemm_bt(const float* __restrict__ A, const short* __restrict__ B,
                          void* __restrict__ Cv, int M, int NC){
  int w = threadIdx.x >> 6, lane = threadIdx.x & 63;
  int row0 = (blockIdx.x*4 + w)*16;
  if (row0 >= M) return;
  int r  = lane & 15;       // A row within tile / B col / C col
  int kq = lane >> 4;       // k-chunk group

  const short* Bhi = B;
  const short* Blo = B + (size_t)NC*FF;

  short8 ahi[4], alo[4];
  const float* arow = A + (size_t)(row0 + r)*FF + kq*8;
  #pragma unroll
  for (int kk = 0; kk < 4; kk++){
    float4 lo4 = *(const float4*)(arow + kk*32);
    float4 hi4 = *(const float4*)(arow + kk*32 + 4);
    float xs[8] = {lo4.x, lo4.y, lo4.z, lo4.w, hi4.x, hi4.y, hi4.z, hi4.w};
    short8 th, tl;
    #pragma unroll
    for (int j = 0; j < 8; j++){
      short h = f2bf(xs[j]);
      th[j] = h;
      tl[j] = f2bf(xs[j] - bf2f(h));
    }
    ahi[kk] = th; alo[kk] = tl;
  }

  for (int ct = 0; ct < (NC >> 4); ct++){
    f32x4 acc = {0.f,0.f,0.f,0.f};
    const short* bh = Bhi + (size_t)(ct*16 + r)*FF + kq*8;
    const short* bl = Blo + (size_t)(ct*16 + r)*FF + kq*8;
    #pragma unroll
    for (int kk = 0; kk < 4; kk++){
      short8 bfh = *(const short8*)(bh + kk*32);
      short8 bfl = *(const short8*)(bl + kk*32);
      acc = __builtin_amdgcn_mfma_f32_16x16x32_bf16(ahi[kk], bfh, acc, 0, 0, 0);
      acc = __builtin_amdgcn_mfma_f32_16x16x32_bf16(ahi[kk], bfl, acc, 0, 0, 0);
      acc = __builtin_amdgcn_mfma_f32_16x16x32_bf16(alo[kk], bfh, acc, 0, 0, 0);
    }
    // D layout: col = lane&15, row = (lane>>4)*4 + reg   [measured m89/m91]
    if (HALF_OUT){
      __half* crow = (__half*)Cv + (size_t)(row0 + kq*4)*NC + ct*16 + r;
      #pragma unroll
      for (int i = 0; i < 4; i++) crow[(size_t)i*NC] = __float2half(acc[i]);
    } else {
      float* crow = (float*)Cv + (size_t)(row0 + kq*4)*NC + ct*16 + r;
      #pragma unroll
      for (int i = 0; i < 4; i++) crow[(size_t)i*NC] = acc[i];
    }
  }
}

// ---- CSR build: histogram, 1-block scan, scatter
__global__ void k_hist(const int* __restrict__ dst, int* __restrict__ deg){
  int e = blockIdx.x*256 + threadIdx.x;
  if (e < NE) atomicAdd(&deg[dst[e]], 1);
}

__global__ void k_scan(const int* __restrict__ deg, int* __restrict__ rowptr,
                       int* __restrict__ cursor){
  __shared__ int sums[1024];
  const int CH = 49;                      // 1024*49 = 50176 >= 50000
  int t = threadIdx.x;
  int base = t*CH;
  int s = 0;
  for (int i = 0; i < CH; i++){ int idx = base+i; if (idx < NN) s += deg[idx]; }
  sums[t] = s; __syncthreads();
  for (int off = 1; off < 1024; off <<= 1){
    int val = (t >= off) ? sums[t-off] : 0;
    __syncthreads();
    sums[t] += val;
    __syncthreads();
  }
  int run = sums[t] - s;                  // exclusive prefix for this chunk
  for (int i = 0; i < CH; i++){
    int idx = base+i;
    if (idx < NN){ rowptr[idx] = run; cursor[idx] = run; run += deg[idx]; }
  }
}

__global__ void k_scatter(const int* __restrict__ src, const int* __restrict__ dst,
                          int* __restrict__ cursor, int2* __restrict__ list){
  int e = blockIdx.x*256 + threadIdx.x;
  if (e < NE){
    int d = dst[e];
    int pos = atomicAdd(&cursor[d], 1);
    list[pos] = make_int2(src[e], e);
  }
}

// ---- fused per-dst: QK dot + bias + clamp + scale + online softmax + gated PV agg
// one wave per node; lane owns features f=2*lane,2*lane+1; head h = lane>>3
// qkv is fp16 [N,384]: q 0-127, k 128-255, v 256-383. list entries batch-loaded
// across lanes then broadcast so per-edge gathers are independent (deep pipeline).
__global__ void k_aggregate(const __half* __restrict__ qkv, const __half* __restrict__ ebg,
                            const int* __restrict__ rowptr, const int* __restrict__ cursor,
                            const int2* __restrict__ list, float* __restrict__ agg){
  int w = threadIdx.x >> 6, lane = threadIdx.x & 63;
  int node = blockIdx.x*4 + w;
  if (node >= NN) return;
  int beg = rowptr[node], end = cursor[node];
  float2 kk = __half22float2(*(const __half2*)&qkv[(size_t)node*384 + 128 + lane*2]);
  int h = lane >> 3;
  float m = -INFINITY, ssum = 0.f, acc0 = 0.f, acc1 = 0.f;
  for (int i0 = beg; i0 < end; i0 += 64){
    int nb = min(end - i0, 64);
    int2 es = (i0 + lane < end) ? list[i0 + lane] : make_int2(0, 0);
    for (int j = 0; j < nb; j++){
      int s = __shfl(es.x, j);
      int e = __shfl(es.y, j);
      const __half* srow = &qkv[(size_t)s*384 + lane*2];
      float2 qq = __half22float2(*(const __half2*)srow);
      float2 vv = __half22float2(*(const __half2*)(srow + 256));
      float bias = __half2float(ebg[(size_t)e*16 + h]);
      float gpre = __half2float(ebg[(size_t)e*16 + 8 + h]);
      float p = qq.x*kk.x + qq.y*kk.y;
      p += __shfl_xor(p, 1); p += __shfl_xor(p, 2); p += __shfl_xor(p, 4);
      float a = fminf(fmaxf(p, -5.f), 5.f);
      float logit = (a + bias)*4.0f;            // /SCALING, SCALING = 1/sqrt(16)
      float mnew = fmaxf(m, logit);
      float corr = __expf(m - mnew);
      float t    = __expf(logit - mnew);
      float g    = 1.f/(1.f + __expf(-gpre));   // sigmoid
      float wgt  = t*g;
      acc0 = acc0*corr + wgt*vv.x;
      acc1 = acc1*corr + wgt*vv.y;
      ssum = ssum*corr + t;
      m = mnew;
    }
  }
  float inv = (end > beg) ? 1.f/ssum : 0.f;
  *(float2*)&agg[(size_t)node*FF + lane*2] = make_float2(acc0*inv, acc1*inv);
}

extern "C" void kernel_launch(void* const* d_in, const int* in_sizes, int n_in,
                              void* d_out, int out_size, void* d_ws, size_t ws_size,
                              hipStream_t stream) {
  const float* feat      = (const float*)d_in[0];
  const float* edge_feat = (const float*)d_in[1];
  const float* Wq        = (const float*)d_in[2];
  const float* Wk        = (const float*)d_in[3];
  const float* Wv        = (const float*)d_in[4];
  const float* Wnode     = (const float*)d_in[5];
  const float* Wedge     = (const float*)d_in[6];
  const float* Wgate     = (const float*)d_in[7];
  const int*   src       = (const int*)d_in[8];
  const int*   dst       = (const int*)d_in[9];
  float* out = (float*)d_out;

  char* p = (char*)d_ws;
  auto alloc = [&](size_t bytes)->char*{
    char* r = p; p += (bytes + 255) & ~(size_t)255; return r;
  };
  __half* qkv   = (__half*)alloc((size_t)NN*384*2);
  __half* ebg   = (__half*)alloc((size_t)NE*16*2);
  float* agg    = (float*)alloc((size_t)NN*FF*4);
  int*   deg    = (int*)  alloc((size_t)NN*4);
  int*   rowptr = (int*)  alloc((size_t)NN*4);
  int*   cursor = (int*)  alloc((size_t)NN*4);
  int2*  list   = (int2*) alloc((size_t)NE*8);
  short* bqkv   = (short*)alloc(2*49152*2);
  short* bn     = (short*)alloc(2*16384*2);
  short* bc     = (short*)alloc(2*2048*2);

  k_cvt_w<<<196, 256, 0, stream>>>(Wq, Wk, Wv, Wnode, Wedge, Wgate, bqkv, bn, bc, deg);

  int gemm_grid_n = (NN/16 + 3)/4;   // 782
  k_gemm_bt<true><<<gemm_grid_n, 256, 0, stream>>>(feat, bqkv, qkv, NN, 384);
  k_gemm_bt<true><<<NE/64, 256, 0, stream>>>(edge_feat, bc, ebg, NE, 16);

  k_hist<<<(NE+255)/256, 256, 0, stream>>>(dst, deg);
  k_scan<<<1, 1024, 0, stream>>>(deg, rowptr, cursor);
  k_scatter<<<(NE+255)/256, 256, 0, stream>>>(src, dst, cursor, list);

  k_aggregate<<<(NN+3)/4, 256, 0, stream>>>(qkv, ebg, rowptr, cursor, list, agg);

  k_gemm_bt<false><<<gemm_grid_n, 256, 0, stream>>>(agg, bn, out, NN, FF);
}